// Round 20
// baseline (27.075 us; speedup 1.0000x reference)
//
#include <hip/hip_runtime.h>
#include <hip/hip_bf16.h>

#define DD 256
#define NROWS 16384
#define BR 64  // rows per block; grid 256 = 1 block/CU

typedef float f32x4 __attribute__((ext_vector_type(4)));
typedef __bf16 bf16x4 __attribute__((ext_vector_type(4)));
typedef __bf16 bf16x8 __attribute__((ext_vector_type(8)));

__device__ __forceinline__ bf16x8 cvt8(f32x4 lo, f32x4 hi) {
  bf16x8 v;
#pragma unroll
  for (int j = 0; j < 4; ++j) {
    v[j] = (__bf16)lo[j];
    v[4 + j] = (__bf16)hi[j];
  }
  return v;
}

// ---------------------------------------------------------------------------
// ONE launch, t-path (no Wc precompute, no second dispatch, no grid sync):
//   t   = bf16(x @ Wv^T + bv)     (32KB LDS, swizzled)
//   out = x + t @ Wout^T + bout
// R8 retried with the lessons since: wave owns 16 cols (not 64) -> 16 weight
// frag loads per GEMM per lane (R8 had 136 -> latency-serialized); af regs
// REUSED across GEMMs (Wv frags -> GEMM1 -> reload Wout frags during barrier
// window -> GEMM2): peak ~90 VGPR. 16 waves x 64 rows/block, grid 256 =
// 1 block/CU (4 waves/SIMD under launch_bounds(1024,4)). Per lane: 36 VMEM.
// Weights (512KB fp32) L2-resident per XCD. Verified machinery: bf16 LDS
// swizzle (R12), reg-frags from global (R13), one-barrier phases (R18),
// LDS bf16 residual (R17), D-layout col=l&15 row=g4*4+reg (R5..R18).
// ---------------------------------------------------------------------------
__global__ __launch_bounds__(1024, 4) void fused_knn(
    const float* __restrict__ x, const float* __restrict__ Wqkv,
    const float* __restrict__ bqkv, const float* __restrict__ Wout,
    const float* __restrict__ bout, float* __restrict__ out) {
  __shared__ __bf16 xs[BR * DD];  // 32 KiB x tile (bf16, swizzled)
  __shared__ __bf16 ts[BR * DD];  // 32 KiB t tile (bf16, swizzled)

  const int t = threadIdx.x;
  const int w = t >> 6, l = t & 63;  // 16 waves
  const int Rbase = blockIdx.x * BR;
  const int xrow = l & 15, g4 = l >> 4;
  const int C0 = w * 16;  // this wave's 16 t-cols / out-cols

  const float* __restrict__ Wv = Wqkv + 2 * DD * DD;
  const float* __restrict__ bv = bqkv + 2 * DD;

  // Per-lane biases for this wave's column quad (hoisted).
  const f32x4 bv4 = *(const f32x4*)(bv + C0 + g4 * 4);
  const f32x4 bo4 = *(const f32x4*)(bout + C0 + g4 * 4);

  // GEMM1 weight frags: Wv row C0+xrow, k = g4*8 + 32ks (16 loads + cvt).
  bf16x8 af[8];
  {
    const float* wvr = Wv + (size_t)(C0 + xrow) * DD + g4 * 8;
#pragma unroll
    for (int ks = 0; ks < 8; ++ks)
      af[ks] = cvt8(*(const f32x4*)(wvr + ks * 32),
                    *(const f32x4*)(wvr + ks * 32 + 4));
  }

  // Stage x tile: 1024 thr -> row sr = t>>4, 16 floats at seg sc = t&15.
  {
    const int sr = t >> 4, sc = t & 15;
    const int ssw = (sr & 7) << 4;
    const int sbase = sr * 512 + sc * 32;
    const float* s0 = x + (size_t)(Rbase + sr) * DD + sc * 16;
    f32x4 a = *(const f32x4*)(s0 + 0);
    f32x4 b = *(const f32x4*)(s0 + 4);
    f32x4 c = *(const f32x4*)(s0 + 8);
    f32x4 d = *(const f32x4*)(s0 + 12);
    *(bf16x8*)((char*)xs + ((sbase + 0) ^ ssw)) = cvt8(a, b);
    *(bf16x8*)((char*)xs + ((sbase + 16) ^ ssw)) = cvt8(c, d);
  }
  __syncthreads();  // barrier 1: xs ready

  // GEMM1: t[:, C0..C0+16) over 4 row tiles; write t quads to ts.
#pragma unroll
  for (int rt = 0; rt < 4; ++rt) {
    const int lrow = rt * 16 + xrow;
    const int lsw = (lrow & 7) << 4;
    bf16x8 xf[8];
#pragma unroll
    for (int ks = 0; ks < 8; ++ks)
      xf[ks] = *(const bf16x8*)((const char*)xs +
                                ((lrow * 512 + ks * 64 + g4 * 16) ^ lsw));
    f32x4 acc = {0.f, 0.f, 0.f, 0.f};
#pragma unroll
    for (int ks = 0; ks < 8; ++ks)
      acc = __builtin_amdgcn_mfma_f32_16x16x32_bf16(af[ks], xf[ks], acc, 0, 0, 0);
    // D: col(l&15) = x-row, rowquad g4*4+reg = t-col offset (verified).
    acc += bv4;
    bf16x4 tq;
#pragma unroll
    for (int j = 0; j < 4; ++j) tq[j] = (__bf16)acc[j];
    *(bf16x4*)((char*)ts + ((lrow * 512 + (C0 + g4 * 4) * 2) ^ lsw)) = tq;
  }

  // Reload af with GEMM2 (Wout) frags -- flies under the barrier wait.
  {
    const float* wor = Wout + (size_t)(C0 + xrow) * DD + g4 * 8;
#pragma unroll
    for (int ks = 0; ks < 8; ++ks)
      af[ks] = cvt8(*(const f32x4*)(wor + ks * 32),
                    *(const f32x4*)(wor + ks * 32 + 4));
  }
  __syncthreads();  // barrier 2: ts ready

  // GEMM2: out[:, C0..C0+16) = x + t @ Wout^T + bout.
#pragma unroll
  for (int rt = 0; rt < 4; ++rt) {
    const int lrow = rt * 16 + xrow;
    const int lsw = (lrow & 7) << 4;
    bf16x8 tf[8];
#pragma unroll
    for (int ks = 0; ks < 8; ++ks)
      tf[ks] = *(const bf16x8*)((const char*)ts +
                                ((lrow * 512 + ks * 64 + g4 * 16) ^ lsw));
    f32x4 acc = {0.f, 0.f, 0.f, 0.f};
#pragma unroll
    for (int ks = 0; ks < 8; ++ks)
      acc = __builtin_amdgcn_mfma_f32_16x16x32_bf16(af[ks], tf[ks], acc, 0, 0, 0);
    const int ocol = C0 + g4 * 4;
    bf16x4 xr4 = *(const bf16x4*)((const char*)xs +
                                  ((lrow * 512 + ocol * 2) ^ lsw));
    f32x4 xres;
#pragma unroll
    for (int j = 0; j < 4; ++j) xres[j] = (float)xr4[j];
    *(f32x4*)(out + (size_t)(Rbase + lrow) * DD + ocol) = acc + xres + bo4;
  }
}

extern "C" void kernel_launch(void* const* d_in, const int* in_sizes, int n_in,
                              void* d_out, int out_size, void* d_ws, size_t ws_size,
                              hipStream_t stream) {
  const float* x = (const float*)d_in[0];
  const float* Wqkv = (const float*)d_in[1];
  const float* bqkv = (const float*)d_in[2];
  const float* Wout = (const float*)d_in[3];
  const float* bout = (const float*)d_in[4];
  float* out = (float*)d_out;

  fused_knn<<<NROWS / BR, 1024, 0, stream>>>(x, Wqkv, bqkv, Wout, bout, out);
}

// Round 21
// 22.282 us; speedup vs baseline: 1.2151x; 1.2151x over previous
//
#include <hip/hip_runtime.h>
#include <hip/hip_bf16.h>

#define DD 256
#define NROWS 16384

typedef float f32x4 __attribute__((ext_vector_type(4)));
typedef __bf16 bf16x4 __attribute__((ext_vector_type(4)));
typedef __bf16 bf16x8 __attribute__((ext_vector_type(8)));

__device__ __forceinline__ bf16x8 cvt8(f32x4 lo, f32x4 hi) {
  bf16x8 v;
#pragma unroll
  for (int j = 0; j < 4; ++j) {
    v[j] = (__bf16)lo[j];
    v[4 + j] = (__bf16)hi[j];
  }
  return v;
}

// ---------------------------------------------------------------------------
// K1: Wc = Wout @ Wv (bf16), bc = bout + Wout @ bv.  [R19 version VERBATIM]
// ---------------------------------------------------------------------------
__global__ __launch_bounds__(1024) void wc_bc_kernel(
    const float* __restrict__ Wqkv, const float* __restrict__ bqkv,
    const float* __restrict__ Wout, const float* __restrict__ bout,
    __bf16* __restrict__ Wc, float* __restrict__ bc) {
  __shared__ float part[16][4][64];  // 16 KiB
  __shared__ float red[4];
  const int b = blockIdx.x;
  const int i0 = (b >> 2) * 4;
  const int qc = b & 3;
  const int c0 = qc * 64;
  const int t = threadIdx.x;
  const int w = t >> 6, l = t & 63;
  const float* __restrict__ Wv = Wqkv + 2 * DD * DD;
  const float* __restrict__ bv = bqkv + 2 * DD;

  float wo[4][16];
#pragma unroll
  for (int r = 0; r < 4; ++r)
#pragma unroll
    for (int jj = 0; jj < 16; ++jj)
      wo[r][jj] = Wout[(size_t)(i0 + r) * DD + w * 16 + jj];

  float acc0 = 0.f, acc1 = 0.f, acc2 = 0.f, acc3 = 0.f;
  const float* wvp = Wv + (size_t)(w * 16) * DD + c0 + l;
#pragma unroll
  for (int jj = 0; jj < 16; ++jj) {
    const float wv = wvp[(size_t)jj * DD];
    acc0 += wo[0][jj] * wv;
    acc1 += wo[1][jj] * wv;
    acc2 += wo[2][jj] * wv;
    acc3 += wo[3][jj] * wv;
  }
  part[w][0][l] = acc0;
  part[w][1][l] = acc1;
  part[w][2][l] = acc2;
  part[w][3][l] = acc3;

  if (qc == 0 && t < 256) {
    const int r = t >> 6, ll = t & 63;
    float p = 0.f;
#pragma unroll
    for (int k = 0; k < 4; ++k)
      p += Wout[(size_t)(i0 + r) * DD + k * 64 + ll] * bv[k * 64 + ll];
#pragma unroll
    for (int off = 32; off > 0; off >>= 1) p += __shfl_down(p, off);
    if (ll == 0) red[r] = p;
  }
  __syncthreads();
  if (t < 256) {
    const int r = t >> 6, ll = t & 63;
    float s = 0.f;
#pragma unroll
    for (int k = 0; k < 16; ++k) s += part[k][r][ll];
    Wc[(size_t)(i0 + r) * DD + c0 + ll] = (__bf16)s;
    if (qc == 0 && ll == 0) bc[i0 + r] = bout[i0 + r] + red[r];
  }
}

// ---------------------------------------------------------------------------
// K2: out = x + x @ Wc^T + bc.  OCCUPANCY experiment (single variable):
// 1024-thr blocks (16 waves), 32 rows; wave owns 16 cols -> af[8] = 32 VGPR
// (half of R18) -> total ~90 VGPR under launch_bounds(1024,2) -> 2 blocks/CU
// = 32 waves/CU = 100% occupancy (R18 measured 38%, latency-bound, all pipes
// idle). Same validated machinery: bf16 swizzled LDS (R12), reg weight frags
// (R13), one barrier (R18), LDS residual (R17), D-layout col=l&15
// row=g4*4+reg (R5..R19). LDS 16KB single buffer; grid 512.
// ---------------------------------------------------------------------------
__global__ __launch_bounds__(1024, 2) void knn_attn_main(
    const float* __restrict__ x, const __bf16* __restrict__ Wc,
    const float* __restrict__ bc, float* __restrict__ out) {
  __shared__ __bf16 xs[32 * DD];  // 16 KiB, swizzled

  const int t = threadIdx.x;
  const int w = t >> 6, l = t & 63;  // 16 waves
  const int Rbase = blockIdx.x * 32;
  const int xrow = l & 15, g4 = l >> 4;
  const int C0 = w * 16;  // this wave's 16 out-cols

  // Weight fragments (32 VGPR) + bias, issued before staging barrier.
  bf16x8 af[8];
  {
    const __bf16* wrp = Wc + (size_t)(C0 + xrow) * DD + g4 * 8;
#pragma unroll
    for (int ks = 0; ks < 8; ++ks) af[ks] = *(const bf16x8*)(wrp + ks * 32);
  }
  const f32x4 bias = *(const f32x4*)(bc + C0 + g4 * 4);  // incl. bout

  // Stage 32 rows: 1024 thr -> row sr = t>>5, 8 floats at seg sc = t&31.
  {
    const int sr = t >> 5, sc = t & 31;
    const int ssw = (sr & 7) << 4;
    const float* s0 = x + (size_t)(Rbase + sr) * DD + sc * 8;
    f32x4 a = *(const f32x4*)(s0);
    f32x4 b = *(const f32x4*)(s0 + 4);
    *(bf16x8*)((char*)xs + ((sr * 512 + sc * 16) ^ ssw)) = cvt8(a, b);
  }
  __syncthreads();  // the ONLY barrier

#pragma unroll
  for (int rt = 0; rt < 2; ++rt) {  // two 16-row tiles
    const int lrow = rt * 16 + xrow;
    const int lsw = (lrow & 7) << 4;
    bf16x8 xf[8];
#pragma unroll
    for (int ks = 0; ks < 8; ++ks)
      xf[ks] = *(const bf16x8*)((const char*)xs +
                                ((lrow * 512 + ks * 64 + g4 * 16) ^ lsw));
    f32x4 acc = {0.f, 0.f, 0.f, 0.f};
#pragma unroll
    for (int ks = 0; ks < 8; ++ks)
      acc = __builtin_amdgcn_mfma_f32_16x16x32_bf16(af[ks], xf[ks], acc, 0, 0, 0);
    // epilogue: D col(l&15)=x-row, rowquad g4*4+reg = out-col (verified).
    const int ocol = C0 + g4 * 4;
    bf16x4 xr4 = *(const bf16x4*)((const char*)xs +
                                  ((lrow * 512 + ocol * 2) ^ lsw));
    f32x4 xres;
#pragma unroll
    for (int j = 0; j < 4; ++j) xres[j] = (float)xr4[j];
    *(f32x4*)(out + (size_t)(Rbase + lrow) * DD + ocol) = acc + xres + bias;
  }
}

extern "C" void kernel_launch(void* const* d_in, const int* in_sizes, int n_in,
                              void* d_out, int out_size, void* d_ws, size_t ws_size,
                              hipStream_t stream) {
  const float* x = (const float*)d_in[0];
  const float* Wqkv = (const float*)d_in[1];
  const float* bqkv = (const float*)d_in[2];
  const float* Wout = (const float*)d_in[3];
  const float* bout = (const float*)d_in[4];
  float* out = (float*)d_out;

  __bf16* Wc = (__bf16*)d_ws;                                   // 128 KiB
  float* bc = (float*)((char*)d_ws + DD * DD * sizeof(__bf16)); // +1 KiB

  wc_bc_kernel<<<DD, 1024, 0, stream>>>(Wqkv, bqkv, Wout, bout, Wc, bc);
  knn_attn_main<<<NROWS / 32, 1024, 0, stream>>>(x, Wc, bc, out);
}